// Round 1
// baseline (176.826 us; speedup 1.0000x reference)
//
#include <hip/hip_runtime.h>

#define PP 7        // PH == PW == 7
#define KK 6        // K
#define SCALE_F 0.0625f

__global__ __launch_bounds__(256) void prroi_fwd(
    const float* __restrict__ feats, const float* __restrict__ rois,
    float* __restrict__ out, int B, int C, int H, int W, int N, int CG)
{
    __shared__ float sWy[PP][KK + 1];
    __shared__ float sWx[PP][KK + 1];
    __shared__ int   sGy[PP][KK + 1];
    __shared__ int   sGx[PP][KK + 1];
    __shared__ float sInv;
    __shared__ int   sBn;

    const int n  = blockIdx.x;
    const int c0 = blockIdx.y * CG;
    const int t  = threadIdx.x;

    if (t < 14) {
        const float* r = rois + (size_t)n * 5;
        const int axis = (t < PP) ? 0 : 1;   // 0 = y, 1 = x
        const int p    = axis ? (t - PP) : t;
        float start, end; int size;
        if (axis == 0) { start = r[2] * SCALE_F; end = r[4] * SCALE_F; size = H; }
        else           { start = r[1] * SCALE_F; end = r[3] * SCALE_F; size = W; }
        const float length = fmaxf(end - start, 0.0f);
        const float binsz  = length / (float)PP;
        const float ws = start + binsz * (float)p;
        const float we = ws + binsz;
        const float s  = floorf(ws);
        float w[KK + 1];
        #pragma unroll
        for (int k = 0; k <= KK; ++k) w[k] = 0.0f;
        #pragma unroll
        for (int k = 0; k < KK; ++k) {
            const float cell = s + (float)k;
            if (cell < we) {                       // strict, matches reference
                const float x0 = fmaxf(ws, cell);
                const float x1 = fminf(we, cell + 1.0f);
                const float a0 = x0 - cell, l0 = x1 - cell;
                w[k]     += l0 - 0.5f * l0 * l0 - a0 + 0.5f * a0 * a0;
                const float a1 = cell + 1.0f - x1, l1 = cell + 1.0f - x0;
                w[k + 1] += l1 - 0.5f * l1 * l1 - a1 + 0.5f * a1 * a1;
            }
        }
        const int si = (int)s;
        #pragma unroll
        for (int k = 0; k <= KK; ++k) {
            const int  idx   = si + k;
            const bool valid = (idx >= 0) && (idx < size);
            const float wv   = valid ? w[k] : 0.0f;
            const int   ic   = min(max(idx, 0), size - 1);
            if (axis == 0) { sWy[p][k] = wv; sGy[p][k] = ic; }
            else           { sWx[p][k] = wv; sGx[p][k] = ic; }
        }
    } else if (t == 14) {
        const float* r = rois + (size_t)n * 5;
        sBn = (int)r[0];
        const float bw  = fmaxf((r[3] - r[1]) * SCALE_F, 0.0f) / (float)PP;
        const float bh  = fmaxf((r[4] - r[2]) * SCALE_F, 0.0f) / (float)PP;
        const float win = bw * bh;
        sInv = (win > 0.0f) ? (1.0f / fmaxf(win, 1e-12f)) : 0.0f;
    }
    __syncthreads();

    const int   bn  = sBn;
    const float inv = sInv;
    const int   HW  = H * W;
    const int total = CG * PP * PP;

    for (int o = t; o < total; o += blockDim.x) {
        const int j = o % PP;
        const int i = (o / PP) % PP;
        const int c = c0 + o / (PP * PP);
        const float* base = feats + (size_t)(bn * C + c) * HW;

        float wy[KK + 1], wx[KK + 1];
        int   gy[KK + 1], gx[KK + 1];
        #pragma unroll
        for (int k = 0; k <= KK; ++k) {
            wy[k] = sWy[i][k]; gy[k] = sGy[i][k];
            wx[k] = sWx[j][k]; gx[k] = sGx[j][k];
        }

        float acc = 0.0f;
        #pragma unroll
        for (int a = 0; a <= KK; ++a) {
            const float* row = base + gy[a] * W;
            float s2 = 0.0f;
            #pragma unroll
            for (int b = 0; b <= KK; ++b)
                s2 = fmaf(wx[b], row[gx[b]], s2);
            acc = fmaf(wy[a], s2, acc);
        }
        out[((size_t)n * C + c) * (PP * PP) + i * PP + j] = acc * inv;
    }
}

extern "C" void kernel_launch(void* const* d_in, const int* in_sizes, int n_in,
                              void* d_out, int out_size, void* d_ws, size_t ws_size,
                              hipStream_t stream) {
    const float* feats = (const float*)d_in[0];
    const float* rois  = (const float*)d_in[1];
    float* out = (float*)d_out;

    const int C = 64, H = 200, W = 304;
    const int B = in_sizes[0] / (C * H * W);
    const int N = in_sizes[1] / 5;

    const int CSPLIT = 4;            // channel groups per roi
    const int CG = C / CSPLIT;       // 16 channels per block
    dim3 grid(N, CSPLIT), block(256);
    hipLaunchKernelGGL(prroi_fwd, grid, block, 0, stream,
                       feats, rois, out, B, C, H, W, N, CG);
}

// Round 2
// 111.367 us; speedup vs baseline: 1.5878x; 1.5878x over previous
//
#include <hip/hip_runtime.h>

#define PP 7        // PH == PW == 7
#define KK 6        // K
#define SCALE_F 0.0625f
#define XMAX 40     // max ROI x-footprint in feature px (<= 37 by construction)
#define CG  16      // channels per block

__global__ __launch_bounds__(256) void prroi_fwd(
    const float* __restrict__ feats, const float* __restrict__ rois,
    float* __restrict__ out, int C, int H, int W)
{
    __shared__ float sWy[PP][KK + 1];
    __shared__ float sWx[PP][KK + 1];
    __shared__ int   sGy[PP][KK + 1];
    __shared__ int   sGx[PP][KK + 1];
    __shared__ float sT[CG][PP][XMAX];   // y-reduced intermediate
    __shared__ float sInv;
    __shared__ int   sBn;

    const int n  = blockIdx.x;
    const int c0 = blockIdx.y * CG;
    const int t  = threadIdx.x;

    // ---- per-roi separable weights (threads 0..14) ----
    if (t < 14) {
        const float* r = rois + (size_t)n * 5;
        const int axis = (t < PP) ? 0 : 1;   // 0 = y, 1 = x
        const int p    = axis ? (t - PP) : t;
        float start, end; int size;
        if (axis == 0) { start = r[2] * SCALE_F; end = r[4] * SCALE_F; size = H; }
        else           { start = r[1] * SCALE_F; end = r[3] * SCALE_F; size = W; }
        const float length = fmaxf(end - start, 0.0f);
        const float binsz  = length / (float)PP;
        const float ws = start + binsz * (float)p;
        const float we = ws + binsz;
        const float s  = floorf(ws);
        float w[KK + 1];
        #pragma unroll
        for (int k = 0; k <= KK; ++k) w[k] = 0.0f;
        #pragma unroll
        for (int k = 0; k < KK; ++k) {
            const float cell = s + (float)k;
            if (cell < we) {                       // strict, matches reference
                const float x0 = fmaxf(ws, cell);
                const float x1 = fminf(we, cell + 1.0f);
                const float a0 = x0 - cell, l0 = x1 - cell;
                w[k]     += l0 - 0.5f * l0 * l0 - a0 + 0.5f * a0 * a0;
                const float a1 = cell + 1.0f - x1, l1 = cell + 1.0f - x0;
                w[k + 1] += l1 - 0.5f * l1 * l1 - a1 + 0.5f * a1 * a1;
            }
        }
        const int si = (int)s;
        #pragma unroll
        for (int k = 0; k <= KK; ++k) {
            const int  idx   = si + k;
            const bool valid = (idx >= 0) && (idx < size);
            const float wv   = valid ? w[k] : 0.0f;
            const int   ic   = min(max(idx, 0), size - 1);
            if (axis == 0) { sWy[p][k] = wv; sGy[p][k] = ic; }
            else           { sWx[p][k] = wv; sGx[p][k] = ic; }
        }
    } else if (t == 14) {
        const float* r = rois + (size_t)n * 5;
        sBn = (int)r[0];
        const float bw  = fmaxf((r[3] - r[1]) * SCALE_F, 0.0f) / (float)PP;
        const float bh  = fmaxf((r[4] - r[2]) * SCALE_F, 0.0f) / (float)PP;
        const float win = bw * bh;
        sInv = (win > 0.0f) ? (1.0f / fmaxf(win, 1e-12f)) : 0.0f;
    }
    __syncthreads();

    const int bn = sBn;
    const int HW = H * W;
    // clamped x-indices are monotone in (j,b) -> min/max at the corners
    const int x0   = sGx[0][0];
    const int span = min(sGx[PP - 1][KK] - x0 + 1, XMAX);

    // ---- pass 1: y-reduction, coalesced along x ----
    const int wave = t >> 6, lane = t & 63;
    for (int p = wave; p < CG * PP; p += 4) {       // one (c,i) row per wave
        const int cl = p / PP;
        const int i  = p % PP;
        const float* base = feats + (size_t)(bn * C + c0 + cl) * HW + x0;
        float wy[KK + 1]; int ro[KK + 1];
        #pragma unroll
        for (int a = 0; a <= KK; ++a) { wy[a] = sWy[i][a]; ro[a] = sGy[i][a] * W; }
        for (int x = lane; x < span; x += 64) {
            float acc = 0.0f;
            #pragma unroll
            for (int a = 0; a <= KK; ++a)
                acc = fmaf(wy[a], base[ro[a] + x], acc);
            sT[cl][i][x] = acc;
        }
    }
    __syncthreads();

    // ---- pass 2: x-reduction from LDS ----
    const float inv = sInv;
    for (int o = t; o < CG * PP * PP; o += 256) {
        const int j  = o % PP;
        const int i  = (o / PP) % PP;
        const int cl = o / (PP * PP);
        float acc = 0.0f;
        #pragma unroll
        for (int b = 0; b <= KK; ++b)
            acc = fmaf(sWx[j][b], sT[cl][i][sGx[j][b] - x0], acc);
        out[((size_t)n * C + c0 + cl) * (PP * PP) + i * PP + j] = acc * inv;
    }
}

extern "C" void kernel_launch(void* const* d_in, const int* in_sizes, int n_in,
                              void* d_out, int out_size, void* d_ws, size_t ws_size,
                              hipStream_t stream) {
    const float* feats = (const float*)d_in[0];
    const float* rois  = (const float*)d_in[1];
    float* out = (float*)d_out;

    const int C = 64, H = 200, W = 304;
    const int N = in_sizes[1] / 5;

    dim3 grid(N, C / CG), block(256);
    hipLaunchKernelGGL(prroi_fwd, grid, block, 0, stream,
                       feats, rois, out, C, H, W);
}

// Round 3
// 106.641 us; speedup vs baseline: 1.6581x; 1.0443x over previous
//
#include <hip/hip_runtime.h>

#define PP 7        // PH == PW == 7
#define KK 6        // K
#define SCALE_F 0.0625f
#define XMAX 40     // max ROI x-footprint in feature px (<= 41, clamped)
#define CG  8       // channels per block

__global__ __launch_bounds__(256) void prroi_fwd(
    const float* __restrict__ feats, const float* __restrict__ rois,
    float* __restrict__ out, int C, int H, int W)
{
    __shared__ float sWy[PP][KK + 1];
    __shared__ float sWx[PP][KK + 1];
    __shared__ int   sGy[PP][KK + 1];
    __shared__ int   sGx[PP][KK + 1];
    __shared__ float sT[CG][PP][XMAX];   // y-reduced intermediate
    __shared__ float sInv;
    __shared__ int   sBn;

    const int n  = blockIdx.x;
    const int c0 = blockIdx.y * CG;
    const int t  = threadIdx.x;

    // ---- per-roi separable weights (threads 0..14) ----
    if (t < 14) {
        const float* r = rois + (size_t)n * 5;
        const int axis = (t < PP) ? 0 : 1;   // 0 = y, 1 = x
        const int p    = axis ? (t - PP) : t;
        float start, end; int size;
        if (axis == 0) { start = r[2] * SCALE_F; end = r[4] * SCALE_F; size = H; }
        else           { start = r[1] * SCALE_F; end = r[3] * SCALE_F; size = W; }
        const float length = fmaxf(end - start, 0.0f);
        const float binsz  = length / (float)PP;
        const float ws = start + binsz * (float)p;
        const float we = ws + binsz;
        const float s  = floorf(ws);
        float w[KK + 1];
        #pragma unroll
        for (int k = 0; k <= KK; ++k) w[k] = 0.0f;
        #pragma unroll
        for (int k = 0; k < KK; ++k) {
            const float cell = s + (float)k;
            if (cell < we) {                       // strict, matches reference
                const float x0 = fmaxf(ws, cell);
                const float x1 = fminf(we, cell + 1.0f);
                const float a0 = x0 - cell, l0 = x1 - cell;
                w[k]     += l0 - 0.5f * l0 * l0 - a0 + 0.5f * a0 * a0;
                const float a1 = cell + 1.0f - x1, l1 = cell + 1.0f - x0;
                w[k + 1] += l1 - 0.5f * l1 * l1 - a1 + 0.5f * a1 * a1;
            }
        }
        const int si = (int)s;
        #pragma unroll
        for (int k = 0; k <= KK; ++k) {
            const int  idx   = si + k;
            const bool valid = (idx >= 0) && (idx < size);
            const float wv   = valid ? w[k] : 0.0f;
            const int   ic   = min(max(idx, 0), size - 1);
            if (axis == 0) { sWy[p][k] = wv; sGy[p][k] = ic; }
            else           { sWx[p][k] = wv; sGx[p][k] = ic; }
        }
    } else if (t == 14) {
        const float* r = rois + (size_t)n * 5;
        sBn = (int)r[0];
        const float bw  = fmaxf((r[3] - r[1]) * SCALE_F, 0.0f) / (float)PP;
        const float bh  = fmaxf((r[4] - r[2]) * SCALE_F, 0.0f) / (float)PP;
        const float win = bw * bh;
        sInv = (win > 0.0f) ? (1.0f / fmaxf(win, 1e-12f)) : 0.0f;
    }
    __syncthreads();

    const int bn = sBn;
    const int HW = H * W;
    // clamped x-indices are monotone in (j,b) -> min/max at the corners
    const int x0   = sGx[0][0];
    const int span = min(sGx[PP - 1][KK] - x0 + 1, XMAX);

    // ---- pass 1: y-reduction, coalesced along x, multi-row lane packing ----
    const int wave = t >> 6, lane = t & 63;
    const int R  = 64 / span;              // rows per wave-load (>=1)
    const int rr = lane / span;            // sub-row within wave
    const int x  = lane - rr * span;
    const bool lactive = (rr < R);
    const float* fbase = feats + (size_t)(bn * C + c0) * HW + x0;

    for (int p0 = wave * R; p0 < CG * PP; p0 += 4 * R) {
        const int p = p0 + rr;
        if (lactive && p < CG * PP) {
            const int cl = p / PP;
            const int i  = p - cl * PP;
            const float* base = fbase + (size_t)cl * HW;
            float acc = 0.0f;
            #pragma unroll
            for (int a = 0; a <= KK; ++a)
                acc = fmaf(sWy[i][a], base[sGy[i][a] * W + x], acc);
            sT[cl][i][x] = acc;
        }
    }
    __syncthreads();

    // ---- pass 2: x-reduction from LDS ----
    const float inv = sInv;
    for (int o = t; o < CG * PP * PP; o += 256) {
        const int j  = o % PP;
        const int i  = (o / PP) % PP;
        const int cl = o / (PP * PP);
        float acc = 0.0f;
        #pragma unroll
        for (int b = 0; b <= KK; ++b)
            acc = fmaf(sWx[j][b], sT[cl][i][sGx[j][b] - x0], acc);
        out[((size_t)n * C + c0 + cl) * (PP * PP) + i * PP + j] = acc * inv;
    }
}

extern "C" void kernel_launch(void* const* d_in, const int* in_sizes, int n_in,
                              void* d_out, int out_size, void* d_ws, size_t ws_size,
                              hipStream_t stream) {
    const float* feats = (const float*)d_in[0];
    const float* rois  = (const float*)d_in[1];
    float* out = (float*)d_out;

    const int C = 64, H = 200, W = 304;
    const int N = in_sizes[1] / 5;

    dim3 grid(N, C / CG), block(256);
    hipLaunchKernelGGL(prroi_fwd, grid, block, 0, stream,
                       feats, rois, out, C, H, W);
}

// Round 4
// 103.400 us; speedup vs baseline: 1.7101x; 1.0313x over previous
//
#include <hip/hip_runtime.h>

#define PP 7        // PH == PW == 7
#define KK 6        // K
#define SCALE_F 0.0625f
#define XMAX 44     // max aligned ROI x-footprint (<= 41 + 3 align slack), mult of 4
#define CG  8       // channels per block

__global__ __launch_bounds__(256) void prroi_fwd(
    const float* __restrict__ feats, const float* __restrict__ rois,
    float* __restrict__ out, int C, int H, int W)
{
    __shared__ float sWy[PP][KK + 1];
    __shared__ float sWx[PP][KK + 1];
    __shared__ int   sGy[PP][KK + 1];
    __shared__ int   sGx[PP][KK + 1];
    __shared__ __align__(16) float sT[CG][PP][XMAX];   // y-reduced intermediate
    __shared__ float sInv;
    __shared__ int   sBn;

    const int n  = blockIdx.x;
    const int c0 = blockIdx.y * CG;
    const int t  = threadIdx.x;

    // ---- per-roi separable weights (threads 0..14) ----
    if (t < 14) {
        const float* r = rois + (size_t)n * 5;
        const int axis = (t < PP) ? 0 : 1;   // 0 = y, 1 = x
        const int p    = axis ? (t - PP) : t;
        float start, end; int size;
        if (axis == 0) { start = r[2] * SCALE_F; end = r[4] * SCALE_F; size = H; }
        else           { start = r[1] * SCALE_F; end = r[3] * SCALE_F; size = W; }
        const float length = fmaxf(end - start, 0.0f);
        const float binsz  = length / (float)PP;
        const float ws = start + binsz * (float)p;
        const float we = ws + binsz;
        const float s  = floorf(ws);
        float w[KK + 1];
        #pragma unroll
        for (int k = 0; k <= KK; ++k) w[k] = 0.0f;
        #pragma unroll
        for (int k = 0; k < KK; ++k) {
            const float cell = s + (float)k;
            if (cell < we) {                       // strict, matches reference
                const float x0 = fmaxf(ws, cell);
                const float x1 = fminf(we, cell + 1.0f);
                const float a0 = x0 - cell, l0 = x1 - cell;
                w[k]     += l0 - 0.5f * l0 * l0 - a0 + 0.5f * a0 * a0;
                const float a1 = cell + 1.0f - x1, l1 = cell + 1.0f - x0;
                w[k + 1] += l1 - 0.5f * l1 * l1 - a1 + 0.5f * a1 * a1;
            }
        }
        const int si = (int)s;
        #pragma unroll
        for (int k = 0; k <= KK; ++k) {
            const int  idx   = si + k;
            const bool valid = (idx >= 0) && (idx < size);
            const float wv   = valid ? w[k] : 0.0f;
            const int   ic   = min(max(idx, 0), size - 1);
            if (axis == 0) { sWy[p][k] = wv; sGy[p][k] = ic; }
            else           { sWx[p][k] = wv; sGx[p][k] = ic; }
        }
    } else if (t == 14) {
        const float* r = rois + (size_t)n * 5;
        sBn = (int)r[0];
        const float bw  = fmaxf((r[3] - r[1]) * SCALE_F, 0.0f) / (float)PP;
        const float bh  = fmaxf((r[4] - r[2]) * SCALE_F, 0.0f) / (float)PP;
        const float win = bw * bh;
        sInv = (win > 0.0f) ? (1.0f / fmaxf(win, 1e-12f)) : 0.0f;
    }
    __syncthreads();

    const int bn = sBn;
    const int HW = H * W;
    // clamped x-indices are monotone in (j,b) -> min/max at the corners
    const int x0a  = sGx[0][0] & ~3;                     // 16B-aligned window start
    const int xmax = sGx[PP - 1][KK];
    const int G    = ((xmax - x0a + 1) + 3) >> 2;        // float4 lanes per row (<=11)
    const int R    = 64 / G;                             // rows per wave-load

    // ---- pass 1: y-reduction, float4-coalesced along x, R rows per wave ----
    const int wave = t >> 6, lane = t & 63;
    const int rr = lane / G;                // sub-row within wave
    const int g  = lane - rr * G;           // float4 slot within row
    // clamp tail loads (start >= W covers only unused cols; keep in-row, aligned)
    const int xcol = min(x0a + 4 * g, W - 4);
    const bool lactive = (rr < R);
    const float* fbase = feats + (size_t)(bn * C + c0) * HW + xcol;

    for (int p0 = wave * R; p0 < CG * PP; p0 += 4 * R) {
        const int p = p0 + rr;
        if (lactive && p < CG * PP) {
            const int cl = p / PP;
            const int i  = p - cl * PP;
            const float* base = fbase + (size_t)cl * HW;
            float4 acc = make_float4(0.f, 0.f, 0.f, 0.f);
            #pragma unroll
            for (int a = 0; a <= KK; ++a) {
                const float wy = sWy[i][a];
                const float4 v = *(const float4*)(base + sGy[i][a] * W);
                acc.x = fmaf(wy, v.x, acc.x);
                acc.y = fmaf(wy, v.y, acc.y);
                acc.z = fmaf(wy, v.z, acc.z);
                acc.w = fmaf(wy, v.w, acc.w);
            }
            ((float4*)&sT[cl][i][0])[g] = acc;
        }
    }
    __syncthreads();

    // ---- pass 2: x-reduction from LDS ----
    const float inv = sInv;
    for (int o = t; o < CG * PP * PP; o += 256) {
        const int j  = o % PP;
        const int i  = (o / PP) % PP;
        const int cl = o / (PP * PP);
        float acc = 0.0f;
        #pragma unroll
        for (int b = 0; b <= KK; ++b)
            acc = fmaf(sWx[j][b], sT[cl][i][sGx[j][b] - x0a], acc);
        out[((size_t)n * C + c0 + cl) * (PP * PP) + i * PP + j] = acc * inv;
    }
}

extern "C" void kernel_launch(void* const* d_in, const int* in_sizes, int n_in,
                              void* d_out, int out_size, void* d_ws, size_t ws_size,
                              hipStream_t stream) {
    const float* feats = (const float*)d_in[0];
    const float* rois  = (const float*)d_in[1];
    float* out = (float*)d_out;

    const int C = 64, H = 200, W = 304;
    const int N = in_sizes[1] / 5;

    dim3 grid(N, C / CG), block(256);
    hipLaunchKernelGGL(prroi_fwd, grid, block, 0, stream,
                       feats, rois, out, C, H, W);
}